// Round 14
// baseline (225.533 us; speedup 1.0000x reference)
//
#include <hip/hip_runtime.h>
#include <math.h>
#include <stdint.h>

#define NROWS 4096
#define CDIM 1024
#define T0_LO 2000
#define T0_HI 10000
#define T1_LO 10000
#define ROOT_COLS 2002
#define ROOT_PAD 2048
#define T0_COLS 8000
#define T0_PAD 8064
#define T1_COLS 40257
#define T1_PAD 40320
#define HB_STRIDE 320
#define LOG2E 1.44269504088896340736f
#define LN2 0.69314718055994530942f

using short8  = __attribute__((ext_vector_type(8))) short;
using ushort8 = __attribute__((ext_vector_type(8))) unsigned short;
using floatx4 = __attribute__((ext_vector_type(4))) float;

__device__ __forceinline__ unsigned short f2bf(float x) {
  union { float f; unsigned int u; } v; v.f = x;
  unsigned int r = v.u + 0x7fffu + ((v.u >> 16) & 1u);
  return (unsigned short)(r >> 16);
}
__device__ __forceinline__ float bf2f(unsigned short h) {
  union { unsigned int u; float f; } v; v.u = ((unsigned int)h) << 16;
  return v.f;
}
__device__ __forceinline__ floatx4 mfma16(short8 a, short8 b, floatx4 c) {
  return __builtin_amdgcn_mfma_f32_16x16x32_bf16(a, b, c, 0, 0, 0);
}
// Async global->LDS 16B: lane i's data lands at lds_wave_base + i*16.
__device__ __forceinline__ void stage16(const unsigned short* g,
                                        unsigned short* lds_wave_base, int lane) {
#if __has_builtin(__builtin_amdgcn_global_load_lds)
  __builtin_amdgcn_global_load_lds(
      (const __attribute__((address_space(1))) void*)g,
      (__attribute__((address_space(3))) void*)lds_wave_base, 16, 0, 0);
#else
  ((ushort8*)lds_wave_base)[lane] = *(const ushort8*)g;
#endif
}

// ---------------- workspace layout (bytes) ----------------
static constexpr size_t B_HB  = 0;                          // ushort[4096*320]
static constexpr size_t B_LB  = B_HB + 4096ull * 320 * 2;   // ushort[4096*1024] bf16 logits
static constexpr size_t B_WP  = B_LB + 4096ull * 1024 * 2;  // ushort[384*1024] (rows 320..383 zero)
static constexpr size_t B_WH  = B_WP + 384ull * 1024 * 2;   // ushort[2048*1024]  (x log2e)
static constexpr size_t B_WS0 = B_WH + 2048ull * 1024 * 2;  // ushort[8064*256]   (x log2e, pad 64)
static constexpr size_t B_WS1 = B_WS0 + 8064ull * 256 * 2;  // ushort[40320*64]   (x log2e, pad 63)
static constexpr size_t B_S   = B_WS1 + 40320ull * 64 * 2;  // float[3*4096]
static constexpr size_t B_P   = B_S + 3ull * 4096 * 4;      // float[3*4096]
static constexpr size_t B_I0  = B_P + 3ull * 4096 * 4;
static constexpr size_t B_I1  = B_I0 + 4096ull * 4;
static constexpr size_t B_CNT = B_I1 + 4096ull * 4;

// ---------------- prep block ranges (explicit END boundaries) ----------------
#define PR_WH_END   2048                     // Wh: 64 x 32 tiles
#define PR_WP0_END  (PR_WH_END + 256)        // proj0: 8 x 32
#define PR_WP1_END  (PR_WP0_END + 64)        // proj1: 2 x 32
#define PR_WS0_END  (PR_WP1_END + 2016)      // scale0: 252 x 8 (Npad 8064)
#define PR_WS1_END  (PR_WS0_END + 2520)      // scale1: 1260 x 2
#define PR_ZERO_END (PR_WS1_END + 32)        // Wp rows 320..383
#define PR_LB_END   (PR_ZERO_END + 2048)     // logits cast
#define PR_S_END    (PR_LB_END + 4)          // S zero
#define PR_TOTAL    (PR_S_END + 1)           // compact (single block, LDS counters)

// zero S + weight transposes (+log2e fold) + Wp pad + logits cast + compact.
__global__ __launch_bounds__(256) void prep_kernel(
    const float* __restrict__ head, const float* __restrict__ proj0,
    const float* __restrict__ proj1, const float* __restrict__ scale0,
    const float* __restrict__ scale1, const float* __restrict__ logits,
    const int* __restrict__ targets,
    unsigned short* __restrict__ Wh, unsigned short* __restrict__ Wp,
    unsigned short* __restrict__ Ws0, unsigned short* __restrict__ Ws1,
    unsigned short* __restrict__ Lb, float* __restrict__ S,
    int* __restrict__ idx0, int* __restrict__ idx1, int* __restrict__ cnt) {
  const int id = blockIdx.x, tid = threadIdx.x;
  if (id >= PR_S_END) {  // compact: one block, LDS counters (cnt written only here)
    __shared__ int base[2];
    if (tid < 2) base[tid] = 0;
    __syncthreads();
    for (int n = tid; n < NROWS; n += 256) {
      int t = targets[n];
      if (t >= T0_LO && t < T0_HI) idx0[atomicAdd(&base[0], 1)] = n;
      else if (t >= T1_LO)         idx1[atomicAdd(&base[1], 1)] = n;
    }
    __syncthreads();
    if (tid < 2) cnt[tid] = base[tid];
    return;
  }
  if (id >= PR_LB_END) {  // zero S (12288 floats over 4 blocks)
    int rel = id - PR_LB_END;
    float4 z = make_float4(0.f, 0.f, 0.f, 0.f);
#pragma unroll
    for (int j = 0; j < 3; j++)
      ((float4*)S)[rel * 768 + j * 256 + tid] = z;
    return;
  }
  if (id >= PR_ZERO_END) {  // logits f32 -> bf16, 2048 elements/block
    size_t base = (size_t)(id - PR_ZERO_END) * 2048 + tid * 8;
    float4 v0 = *(const float4*)(logits + base);
    float4 v1 = *(const float4*)(logits + base + 4);
    ushort8 h;
    h[0] = f2bf(v0.x); h[1] = f2bf(v0.y); h[2] = f2bf(v0.z); h[3] = f2bf(v0.w);
    h[4] = f2bf(v1.x); h[5] = f2bf(v1.y); h[6] = f2bf(v1.z); h[7] = f2bf(v1.w);
    *(ushort8*)(Lb + base) = h;
    return;
  }
  if (id >= PR_WS1_END) {  // zero Wp rows 320..383: 32 blocks x 2048 ushorts
    size_t off = (size_t)(id - PR_WS1_END) * 2048 + tid * 8;
    ushort8 z = {0, 0, 0, 0, 0, 0, 0, 0};
    *(ushort8*)(Wp + 320ull * 1024 + off) = z;
    return;
  }
  const float* W; unsigned short* Wt; int K, N, Npad, nx, rel; float scale;
  if (id < PR_WH_END)       { W = head;   Wt = Wh;  K = 1024; N = ROOT_COLS; Npad = ROOT_PAD; scale = LOG2E; nx = 64;   rel = id; }
  else if (id < PR_WP0_END) { W = proj0;  Wt = Wp;  K = 1024; N = 256;  Npad = 256;  scale = 1.f;  nx = 8;    rel = id - PR_WH_END; }
  else if (id < PR_WP1_END) { W = proj1;  Wt = Wp + 256 * 1024; K = 1024; N = 64; Npad = 64; scale = 1.f; nx = 2; rel = id - PR_WP0_END; }
  else if (id < PR_WS0_END) { W = scale0; Wt = Ws0; K = 256;  N = T0_COLS; Npad = T0_PAD; scale = LOG2E; nx = 252;  rel = id - PR_WP1_END; }
  else                      { W = scale1; Wt = Ws1; K = 64;   N = T1_COLS; Npad = T1_PAD; scale = LOG2E; nx = 1260; rel = id - PR_WS0_END; }
  __shared__ float tile[32][33];
  const int n0 = (rel % nx) * 32, k0 = (rel / nx) * 32;
  const int tx = tid & 31, ty = tid >> 5;  // 32 x 8
  for (int i = 0; i < 32; i += 8) {
    int k = k0 + ty + i, n = n0 + tx;
    tile[ty + i][tx] = (n < N) ? W[(size_t)k * N + n] * scale : 0.f;
  }
  __syncthreads();
  // vectorized write: each thread emits 4 consecutive k as one 8 B store
  const int nloc = tid >> 3, kg = tid & 7;
  const int n = n0 + nloc;
  if (n < Npad) {
    union { unsigned short v[4]; uint2 u; } x;
#pragma unroll
    for (int j = 0; j < 4; j++) x.v[j] = f2bf(tile[kg * 4 + j][nloc]);
    *(uint2*)&Wt[(size_t)n * K + k0 + kg * 4] = x.u;
  }
}

// Shared 64-row x CI-cg x K=1024 MFMA K-loop. DOUBLE-BUFFERED: KC=128 in two
// 16 KB halves; chunk h+1's DMA is issued AFTER the barrier so the NEXT
// barrier's vmcnt drain finds it landed (a full compute phase of cover).
// One barrier per chunk (r13 single-buffer: 2 barriers + exposed DMA latency).
template<int CI>
__device__ __forceinline__ void gemm64_kloop(
    unsigned short* A_lds,   // 2 x (64*128) ushorts = 32 KB
    const unsigned short* Arow,
    const unsigned short* const (&Bbase)[CI],
    floatx4 (&acc)[CI][4], int tid) {
  const int lane = tid & 63, w = tid >> 6;
  const int m = lane & 15, quad = lane >> 4, keym = m & 7;
  // slot s = w*256+it*64+lane: row r=s>>4, phys p=s&15, logical cq = p^(r&7)
  int goff[4];
#pragma unroll
  for (int it = 0; it < 4; it++) {
    int s = w * 256 + it * 64 + lane;
    int r = s >> 4, p = s & 15;
    int cq = p ^ (r & 7);
    goff[it] = r * CDIM + cq * 8;
  }
  // prologue: stage chunk 0 into half 0
#pragma unroll
  for (int it = 0; it < 4; it++)
    stage16(Arow + goff[it], &A_lds[(w * 256 + it * 64) * 8], lane);
  for (int h = 0; h < 8; h++) {
    unsigned short* cur = A_lds + (h & 1) * (64 * 128);
    unsigned short* nxt = A_lds + ((h + 1) & 1) * (64 * 128);
    __syncthreads();  // drains chunk-h DMA (issued one compute phase ago);
                      // also: all readers of nxt's previous contents are done
    if (h + 1 < 8) {
#pragma unroll
      for (int it = 0; it < 4; it++)
        stage16(Arow + goff[it] + (h + 1) * 128,
                &nxt[(w * 256 + it * 64) * 8], lane);
    }
    short8 b[CI][4];
#pragma unroll
    for (int ci = 0; ci < CI; ci++)
#pragma unroll
      for (int ks = 0; ks < 4; ks++)
        b[ci][ks] = *(const short8*)(Bbase[ci] + h * 128 + ks * 32);
    short8 areg[4][4];
#pragma unroll
    for (int t = 0; t < 4; t++)
#pragma unroll
      for (int ks = 0; ks < 4; ks++) {
        int ch = ((ks << 2) + quad) ^ keym;
        areg[t][ks] = *(const short8*)&cur[(t * 16 + m) * 128 + (ch << 3)];
      }
#pragma unroll
    for (int ci = 0; ci < CI; ci++)
#pragma unroll
      for (int ks = 0; ks < 4; ks++)
#pragma unroll
        for (int t = 0; t < 4; t++)
          acc[ci][t] = mfma16(areg[t][ks], b[ci][ks], acc[ci][t]);
  }
}

// Hidden projection: Hb[4096][320] = bf16(Lb @ Wp). CPS=1, grid (64,5).
__global__ __launch_bounds__(256) void gemm_hidden(
    const unsigned short* __restrict__ Lb,
    const unsigned short* __restrict__ Wp,
    unsigned short* __restrict__ Hb) {
  __shared__ unsigned short A_lds[64 * 256];  // 2 x 16 KB halves
  const int tid = threadIdx.x;
  const int row0 = blockIdx.x * 64;
  const int cg0 = blockIdx.y;
  const int lane = tid & 63, w = tid >> 6;
  const int m = lane & 15, quad = lane >> 4;
  const floatx4 zf = {0.f, 0.f, 0.f, 0.f};
  floatx4 acc[1][4];
#pragma unroll
  for (int t = 0; t < 4; t++) acc[0][t] = zf;
  const unsigned short* Bb[1] = {
      Wp + (size_t)(cg0 * 64 + w * 16 + m) * CDIM + quad * 8};
  gemm64_kloop<1>(A_lds, Lb + (size_t)row0 * CDIM, Bb, acc, tid);
  int n = cg0 * 64 + w * 16 + m;
  if (n < HB_STRIDE) {
#pragma unroll
    for (int t = 0; t < 4; t++)
#pragma unroll
      for (int r = 0; r < 4; r++)
        Hb[(size_t)(row0 + t * 16 + quad * 4 + r) * HB_STRIDE + n] =
            f2bf(acc[0][t][r]);
  }
}

// ---------------- mega kernel: root CE + tail1 + tail0 + picked ----------------
#define MG_ROOT 1024          // 64 x-tiles x 16 cg-pairs      (32 chunks)
#define MG_T1   480           // 32 row-tiles (BM=128) x 15 y  (15 chunks)
#define MG_T0   2688          // 128 row-tiles x 21 y          (84 chunks)
#define MG_PICK 1024          //                               (32 chunks)
#define MG_TOTAL (MG_ROOT + MG_T1 + MG_T0 + MG_PICK)  // 5216 = 163*32, 163 prime

__device__ __forceinline__ void root_path(
    unsigned char* smem, int bx, int by,
    const unsigned short* __restrict__ Lb,
    const unsigned short* __restrict__ Wh, float* __restrict__ S) {
  unsigned short* A_lds = (unsigned short*)smem;  // 2 x 16 KB
  const int tid = threadIdx.x;
  const int row0 = bx * 64;
  const int cg0 = by * 2;
  const int lane = tid & 63, w = tid >> 6;
  const int m = lane & 15, quad = lane >> 4;
  const floatx4 zf = {0.f, 0.f, 0.f, 0.f};
  floatx4 acc[2][4];
#pragma unroll
  for (int ci = 0; ci < 2; ci++)
#pragma unroll
    for (int t = 0; t < 4; t++) acc[ci][t] = zf;
  const unsigned short* Bb[2] = {
      Wh + (size_t)((cg0 + 0) * 64 + w * 16 + m) * CDIM + quad * 8,
      Wh + (size_t)((cg0 + 1) * 64 + w * 16 + m) * CDIM + quad * 8};
  gemm64_kloop<2>(A_lds, Lb + (size_t)row0 * CDIM, Bb, acc, tid);
  // epilogue: reuse smem as the per-row sum buffer (A dead after K-loop)
  __syncthreads();
  float* sums = (float*)smem;
  if (tid < 64) sums[tid] = 0.f;
  __syncthreads();
#pragma unroll
  for (int t = 0; t < 4; t++)
#pragma unroll
    for (int r = 0; r < 4; r++) {
      float e = __builtin_amdgcn_exp2f(acc[0][t][r]) +
                __builtin_amdgcn_exp2f(acc[1][t][r]);
      e += __shfl_xor(e, 1); e += __shfl_xor(e, 2);
      e += __shfl_xor(e, 4); e += __shfl_xor(e, 8);
      if (m == 0) atomicAdd(&sums[t * 16 + quad * 4 + r], e);
    }
  __syncthreads();
  if (tid < 64) atomicAdd(&S[row0 + tid], sums[tid]);
}

// Tail CE path: A in regs, runtime cg loop, 2 cgs/iter through literally-
// indexed b0/b1 with 2-deep prefetch (r6/r9 register lessons).
template<int K, int TILES, int MODE>
__device__ __forceinline__ void tail_path(
    unsigned char* smem, int bx, int by,
    const unsigned short* __restrict__ Hb, int acol0,
    const unsigned short* __restrict__ Wt, int ncgpb,
    const int* __restrict__ idx, const int* __restrict__ cnt,
    float* __restrict__ S) {
  constexpr int BM = TILES * 16;
  constexpr int CpR = K / 8;
  constexpr int KS = K / 32;
  unsigned short* A_lds = (unsigned short*)smem;            // BM*K ushorts
  int* row_lds = (int*)(smem + (size_t)BM * K * 2);
  float* sum_lds = (float*)(smem + (size_t)BM * K * 2 + BM * 4);
  const int tid = threadIdx.x;
  const int count = cnt[MODE - 1];
  const int row0 = bx * BM;
  if (row0 >= count) return;
  if (tid < BM) {
    int r = row0 + tid;
    row_lds[tid] = (r < count) ? idx[r] : -1;
    sum_lds[tid] = 0.f;
  }
  __syncthreads();
#pragma unroll
  for (int i = 0; i < BM * CpR / 256; i++) {
    int c = tid + 256 * i;
    int rl = c / CpR, cq = c % CpR;
    int row = row_lds[rl];
    ushort8 v = {0, 0, 0, 0, 0, 0, 0, 0};
    if (row >= 0) v = *(const ushort8*)(Hb + (size_t)row * HB_STRIDE + acol0 + cq * 8);
    *(ushort8*)&A_lds[rl * K + ((cq ^ (rl & 7)) << 3)] = v;
  }
  __syncthreads();
  const int lane = tid & 63, w = tid >> 6;
  const int m = lane & 15, quad = lane >> 4, keym = m & 7;
  const floatx4 zf = {0.f, 0.f, 0.f, 0.f};
  short8 areg[TILES][KS];
#pragma unroll
  for (int t = 0; t < TILES; t++)
#pragma unroll
    for (int ks = 0; ks < KS; ks++) {
      int ch = ((ks << 2) + quad) ^ keym;
      areg[t][ks] = *(const short8*)&A_lds[(t * 16 + m) * K + (ch << 3)];
    }
  float runsum[TILES][4];
#pragma unroll
  for (int t = 0; t < TILES; t++)
#pragma unroll
    for (int r = 0; r < 4; r++) runsum[t][r] = 0.f;

  const int cg0 = by * ncgpb;
  const unsigned short* Bp = Wt + (size_t)(cg0 * 64 + w * 16 + m) * K + quad * 8;
  short8 b0[KS], b1[KS];
#pragma unroll
  for (int ks = 0; ks < KS; ks++) b0[ks] = *(const short8*)(Bp + ks * 32);
#pragma unroll
  for (int ks = 0; ks < KS; ks++)
    b1[ks] = *(const short8*)(Bp + (size_t)64 * K + ks * 32);

  for (int cc = 0; cc < ncgpb; cc += 2) {  // runtime loop, literal reg indices
    floatx4 acc[TILES];
#pragma unroll
    for (int t = 0; t < TILES; t++) acc[t] = zf;
#pragma unroll
    for (int ks = 0; ks < KS; ks++)
#pragma unroll
      for (int t = 0; t < TILES; t++) acc[t] = mfma16(areg[t][ks], b0[ks], acc[t]);
    if (cc + 2 < ncgpb) {
      const unsigned short* p = Bp + (size_t)(cc + 2) * 64 * K;
#pragma unroll
      for (int ks = 0; ks < KS; ks++) b0[ks] = *(const short8*)(p + ks * 32);
    }
#pragma unroll
    for (int t = 0; t < TILES; t++)
#pragma unroll
      for (int r = 0; r < 4; r++)
        runsum[t][r] += __builtin_amdgcn_exp2f(acc[t][r]);

#pragma unroll
    for (int t = 0; t < TILES; t++) acc[t] = zf;
#pragma unroll
    for (int ks = 0; ks < KS; ks++)
#pragma unroll
      for (int t = 0; t < TILES; t++) acc[t] = mfma16(areg[t][ks], b1[ks], acc[t]);
    if (cc + 3 < ncgpb) {
      const unsigned short* p = Bp + (size_t)(cc + 3) * 64 * K;
#pragma unroll
      for (int ks = 0; ks < KS; ks++) b1[ks] = *(const short8*)(p + ks * 32);
    }
#pragma unroll
    for (int t = 0; t < TILES; t++)
#pragma unroll
      for (int r = 0; r < 4; r++)
        runsum[t][r] += __builtin_amdgcn_exp2f(acc[t][r]);
  }

#pragma unroll
  for (int t = 0; t < TILES; t++)
#pragma unroll
    for (int r = 0; r < 4; r++) {
      float e = runsum[t][r];
      e += __shfl_xor(e, 1); e += __shfl_xor(e, 2);
      e += __shfl_xor(e, 4); e += __shfl_xor(e, 8);
      if (m == 0) atomicAdd(&sum_lds[t * 16 + quad * 4 + r], e);
    }
  __syncthreads();
  if (tid < BM) {
    int row = row_lds[tid];
    if (row >= 0) atomicAdd(&S[row], sum_lds[tid]);
  }
}

__device__ __forceinline__ void picked_path(
    int rel, const float* __restrict__ logits, const int* __restrict__ targets,
    const unsigned short* __restrict__ Wh,
    const unsigned short* __restrict__ Ws0,
    const unsigned short* __restrict__ Ws1,
    const unsigned short* __restrict__ Hb, float* __restrict__ P) {
  const int tid = threadIdx.x, lane = tid & 63;
  const int row = rel * 4 + (tid >> 6);
  const int t = targets[row];
  const int tr = (t >= T0_LO && t < T0_HI) ? T0_LO : ((t >= T1_LO) ? T0_LO + 1 : t);
  const float* a = logits + (size_t)row * CDIM + lane * 16;
  const unsigned short* wr = Wh + (size_t)tr * CDIM + lane * 16;
  float acc = 0.f;
#pragma unroll
  for (int q = 0; q < 2; q++) {
    ushort8 wv = *(const ushort8*)(wr + q * 8);
    float4 a0 = ((const float4*)a)[q * 2];
    float4 a1 = ((const float4*)a)[q * 2 + 1];
    acc += a0.x * bf2f(wv[0]) + a0.y * bf2f(wv[1]) + a0.z * bf2f(wv[2]) + a0.w * bf2f(wv[3]);
    acc += a1.x * bf2f(wv[4]) + a1.y * bf2f(wv[5]) + a1.z * bf2f(wv[6]) + a1.w * bf2f(wv[7]);
  }
#pragma unroll
  for (int off = 1; off < 64; off <<= 1) acc += __shfl_xor(acc, off);
  if (lane == 0) P[row] = acc * LN2;
  if (t >= T0_LO) {
    float acc2 = 0.f;
    if (t < T0_HI) {
      const unsigned short* h = Hb + (size_t)row * HB_STRIDE + lane * 4;
      const unsigned short* w2 = Ws0 + (size_t)(t - T0_LO) * 256 + lane * 4;
#pragma unroll
      for (int j = 0; j < 4; j++) acc2 += bf2f(h[j]) * bf2f(w2[j]);
    } else {
      acc2 = bf2f(Hb[(size_t)row * HB_STRIDE + 256 + lane]) *
             bf2f(Ws1[(size_t)(t - T1_LO) * 64 + lane]);
    }
#pragma unroll
    for (int off = 1; off < 64; off <<= 1) acc2 += __shfl_xor(acc2, off);
    if (lane == 0) P[(t < T0_HI ? NROWS : 2 * NROWS) + row] = acc2 * LN2;
  }
}

__global__ __launch_bounds__(256, 2) void mega_kernel(
    const unsigned short* __restrict__ Lb,
    const unsigned short* __restrict__ Wh,
    const unsigned short* __restrict__ Ws0,
    const unsigned short* __restrict__ Ws1,
    const unsigned short* __restrict__ Hb,
    const float* __restrict__ logits, const int* __restrict__ targets,
    const int* __restrict__ idx0, const int* __restrict__ idx1,
    const int* __restrict__ cnt, float* __restrict__ S, float* __restrict__ P) {
  __shared__ __align__(16) unsigned char smem[32768];
  // interleave block TYPES at 32-block chunk granularity (5216 = 163*32,
  // 163 prime, 37 coprime -> bijection). Chunks keep their cg/B locality;
  // resident per-CU mix becomes root+tail+picked -> mutual latency hiding.
  int chunk = blockIdx.x >> 5;
  int bid = ((chunk * 37) % 163) * 32 + (blockIdx.x & 31);
  if (bid < MG_ROOT) {
    root_path(smem, bid & 63, bid >> 6, Lb, Wh, S);
    return;
  }
  bid -= MG_ROOT;
  if (bid < MG_T1) {  // BM=128: x = bid & 31 (row-tile), y = bid >> 5
    tail_path<64, 8, 2>(smem, bid & 31, bid >> 5, Hb, 256, Ws1, 42, idx1, cnt,
                        S + 2 * NROWS);
    return;
  }
  bid -= MG_T1;
  if (bid < MG_T0) {
    tail_path<256, 2, 1>(smem, bid & 127, bid >> 7, Hb, 0, Ws0, 6, idx0, cnt,
                         S + NROWS);
    return;
  }
  bid -= MG_T0;
  picked_path(bid, logits, targets, Wh, Ws0, Ws1, Hb, P);
}

__global__ void loss_kernel(const int* __restrict__ targets,
                            const float* __restrict__ S,   // [3][NROWS]
                            const float* __restrict__ P,   // [3][NROWS]
                            float* __restrict__ out) {
  const int tid = threadIdx.x;
  float sr = 0.f, s0 = 0.f, s1 = 0.f, c0 = 0.f, c1 = 0.f;
  for (int n = tid; n < NROWS; n += 256) {
    int t = targets[n];
    sr += logf(S[n] - 46.f) - P[n];  // 46 root pad cols -> exp2(0)=1 each
    if (t >= T0_LO && t < T0_HI) { s0 += logf(S[NROWS + n] - 64.f) - P[NROWS + n]; c0 += 1.f; }
    else if (t >= T1_LO)         { s1 += logf(S[2 * NROWS + n] - 63.f) - P[2 * NROWS + n]; c1 += 1.f; }
  }
  for (int off = 32; off > 0; off >>= 1) {
    sr += __shfl_down(sr, off);
    s0 += __shfl_down(s0, off);
    s1 += __shfl_down(s1, off);
    c0 += __shfl_down(c0, off);
    c1 += __shfl_down(c1, off);
  }
  __shared__ float red[4][5];
  int wv = tid >> 6;
  if ((tid & 63) == 0) { red[wv][0] = sr; red[wv][1] = s0; red[wv][2] = s1; red[wv][3] = c0; red[wv][4] = c1; }
  __syncthreads();
  if (tid == 0) {
    sr = red[0][0] + red[1][0] + red[2][0] + red[3][0];
    s0 = red[0][1] + red[1][1] + red[2][1] + red[3][1];
    s1 = red[0][2] + red[1][2] + red[2][2] + red[3][2];
    c0 = red[0][3] + red[1][3] + red[2][3] + red[3][3];
    c1 = red[0][4] + red[1][4] + red[2][4] + red[3][4];
    float root_loss = sr / (float)NROWS;
    float l0 = s0 / fmaxf(c0, 1.f);
    float l1 = s1 / fmaxf(c1, 1.f);
    out[0] = (root_loss + l0 + l1) / 3.f;
  }
}

extern "C" void kernel_launch(void* const* d_in, const int* in_sizes, int n_in,
                              void* d_out, int out_size, void* d_ws, size_t ws_size,
                              hipStream_t stream) {
  const float* logits  = (const float*)d_in[0];
  const int*   targets = (const int*)d_in[1];
  const float* head    = (const float*)d_in[2];
  const float* proj0   = (const float*)d_in[3];
  const float* scale0  = (const float*)d_in[4];
  const float* proj1   = (const float*)d_in[5];
  const float* scale1  = (const float*)d_in[6];
  float* out = (float*)d_out;
  char* ws = (char*)d_ws;

  unsigned short* Hb  = (unsigned short*)(ws + B_HB);
  unsigned short* Lb  = (unsigned short*)(ws + B_LB);
  unsigned short* Wp  = (unsigned short*)(ws + B_WP);
  unsigned short* Wh  = (unsigned short*)(ws + B_WH);
  unsigned short* Ws0 = (unsigned short*)(ws + B_WS0);
  unsigned short* Ws1 = (unsigned short*)(ws + B_WS1);
  float* S = (float*)(ws + B_S);
  float* P = (float*)(ws + B_P);
  int* idx0 = (int*)(ws + B_I0);
  int* idx1 = (int*)(ws + B_I1);
  int* cnt  = (int*)(ws + B_CNT);

  prep_kernel<<<PR_TOTAL, 256, 0, stream>>>(head, proj0, proj1, scale0, scale1,
                                            logits, targets, Wh, Wp, Ws0, Ws1,
                                            Lb, S, idx0, idx1, cnt);
  gemm_hidden<<<dim3(64, 5), 256, 0, stream>>>(Lb, Wp, Hb);
  mega_kernel<<<MG_TOTAL, 256, 0, stream>>>(Lb, Wh, Ws0, Ws1, Hb, logits,
                                            targets, idx0, idx1, cnt, S, P);
  loss_kernel<<<1, 256, 0, stream>>>(targets, S, P, out);
}

// Round 15
// 205.615 us; speedup vs baseline: 1.0969x; 1.0969x over previous
//
#include <hip/hip_runtime.h>
#include <math.h>
#include <stdint.h>

#define NROWS 4096
#define CDIM 1024
#define T0_LO 2000
#define T0_HI 10000
#define T1_LO 10000
#define ROOT_COLS 2002
#define ROOT_PAD 2048
#define T0_COLS 8000
#define T0_PAD 8064
#define T1_COLS 40257
#define T1_PAD 40320
#define HB_STRIDE 320
#define LOG2E 1.44269504088896340736f
#define LN2 0.69314718055994530942f

using short8  = __attribute__((ext_vector_type(8))) short;
using ushort8 = __attribute__((ext_vector_type(8))) unsigned short;
using floatx4 = __attribute__((ext_vector_type(4))) float;

__device__ __forceinline__ unsigned short f2bf(float x) {
  union { float f; unsigned int u; } v; v.f = x;
  unsigned int r = v.u + 0x7fffu + ((v.u >> 16) & 1u);
  return (unsigned short)(r >> 16);
}
__device__ __forceinline__ float bf2f(unsigned short h) {
  union { unsigned int u; float f; } v; v.u = ((unsigned int)h) << 16;
  return v.f;
}
__device__ __forceinline__ floatx4 mfma16(short8 a, short8 b, floatx4 c) {
  return __builtin_amdgcn_mfma_f32_16x16x32_bf16(a, b, c, 0, 0, 0);
}
// Async global->LDS 16B: lane i's data lands at lds_wave_base + i*16.
__device__ __forceinline__ void stage16(const unsigned short* g,
                                        unsigned short* lds_wave_base, int lane) {
#if __has_builtin(__builtin_amdgcn_global_load_lds)
  __builtin_amdgcn_global_load_lds(
      (const __attribute__((address_space(1))) void*)g,
      (__attribute__((address_space(3))) void*)lds_wave_base, 16, 0, 0);
#else
  ((ushort8*)lds_wave_base)[lane] = *(const ushort8*)g;
#endif
}

// ---------------- workspace layout (bytes) ----------------
static constexpr size_t B_HB  = 0;                          // ushort[4096*320]
static constexpr size_t B_LB  = B_HB + 4096ull * 320 * 2;   // ushort[4096*1024] bf16 logits
static constexpr size_t B_WP  = B_LB + 4096ull * 1024 * 2;  // ushort[384*1024] (rows 320..383 zero)
static constexpr size_t B_WH  = B_WP + 384ull * 1024 * 2;   // ushort[2048*1024]  (x log2e)
static constexpr size_t B_WS0 = B_WH + 2048ull * 1024 * 2;  // ushort[8064*256]   (x log2e, pad 64)
static constexpr size_t B_WS1 = B_WS0 + 8064ull * 256 * 2;  // ushort[40320*64]   (x log2e, pad 63)
static constexpr size_t B_S   = B_WS1 + 40320ull * 64 * 2;  // float[3*4096]
static constexpr size_t B_P   = B_S + 3ull * 4096 * 4;      // float[3*4096]
static constexpr size_t B_I0  = B_P + 3ull * 4096 * 4;
static constexpr size_t B_I1  = B_I0 + 4096ull * 4;
static constexpr size_t B_CNT = B_I1 + 4096ull * 4;

// ---------------- prep block ranges (explicit END boundaries) ----------------
#define PR_WH_END   2048                     // Wh: 64 x 32 tiles
#define PR_WP0_END  (PR_WH_END + 256)        // proj0: 8 x 32
#define PR_WP1_END  (PR_WP0_END + 64)        // proj1: 2 x 32
#define PR_WS0_END  (PR_WP1_END + 2016)      // scale0: 252 x 8 (Npad 8064)
#define PR_WS1_END  (PR_WS0_END + 2520)      // scale1: 1260 x 2
#define PR_ZERO_END (PR_WS1_END + 32)        // Wp rows 320..383
#define PR_LB_END   (PR_ZERO_END + 2048)     // logits cast
#define PR_S_END    (PR_LB_END + 4)          // S zero
#define PR_TOTAL    (PR_S_END + 1)           // compact (single block, LDS counters)

// zero S + weight transposes (+log2e fold) + Wp pad + logits cast + compact.
__global__ __launch_bounds__(256) void prep_kernel(
    const float* __restrict__ head, const float* __restrict__ proj0,
    const float* __restrict__ proj1, const float* __restrict__ scale0,
    const float* __restrict__ scale1, const float* __restrict__ logits,
    const int* __restrict__ targets,
    unsigned short* __restrict__ Wh, unsigned short* __restrict__ Wp,
    unsigned short* __restrict__ Ws0, unsigned short* __restrict__ Ws1,
    unsigned short* __restrict__ Lb, float* __restrict__ S,
    int* __restrict__ idx0, int* __restrict__ idx1, int* __restrict__ cnt) {
  const int id = blockIdx.x, tid = threadIdx.x;
  if (id >= PR_S_END) {  // compact: one block, LDS counters (cnt written only here)
    __shared__ int base[2];
    if (tid < 2) base[tid] = 0;
    __syncthreads();
    for (int n = tid; n < NROWS; n += 256) {
      int t = targets[n];
      if (t >= T0_LO && t < T0_HI) idx0[atomicAdd(&base[0], 1)] = n;
      else if (t >= T1_LO)         idx1[atomicAdd(&base[1], 1)] = n;
    }
    __syncthreads();
    if (tid < 2) cnt[tid] = base[tid];
    return;
  }
  if (id >= PR_LB_END) {  // zero S (12288 floats over 4 blocks)
    int rel = id - PR_LB_END;
    float4 z = make_float4(0.f, 0.f, 0.f, 0.f);
#pragma unroll
    for (int j = 0; j < 3; j++)
      ((float4*)S)[rel * 768 + j * 256 + tid] = z;
    return;
  }
  if (id >= PR_ZERO_END) {  // logits f32 -> bf16, 2048 elements/block
    size_t base = (size_t)(id - PR_ZERO_END) * 2048 + tid * 8;
    float4 v0 = *(const float4*)(logits + base);
    float4 v1 = *(const float4*)(logits + base + 4);
    ushort8 h;
    h[0] = f2bf(v0.x); h[1] = f2bf(v0.y); h[2] = f2bf(v0.z); h[3] = f2bf(v0.w);
    h[4] = f2bf(v1.x); h[5] = f2bf(v1.y); h[6] = f2bf(v1.z); h[7] = f2bf(v1.w);
    *(ushort8*)(Lb + base) = h;
    return;
  }
  if (id >= PR_WS1_END) {  // zero Wp rows 320..383: 32 blocks x 2048 ushorts
    size_t off = (size_t)(id - PR_WS1_END) * 2048 + tid * 8;
    ushort8 z = {0, 0, 0, 0, 0, 0, 0, 0};
    *(ushort8*)(Wp + 320ull * 1024 + off) = z;
    return;
  }
  const float* W; unsigned short* Wt; int K, N, Npad, nx, rel; float scale;
  if (id < PR_WH_END)       { W = head;   Wt = Wh;  K = 1024; N = ROOT_COLS; Npad = ROOT_PAD; scale = LOG2E; nx = 64;   rel = id; }
  else if (id < PR_WP0_END) { W = proj0;  Wt = Wp;  K = 1024; N = 256;  Npad = 256;  scale = 1.f;  nx = 8;    rel = id - PR_WH_END; }
  else if (id < PR_WP1_END) { W = proj1;  Wt = Wp + 256 * 1024; K = 1024; N = 64; Npad = 64; scale = 1.f; nx = 2; rel = id - PR_WP0_END; }
  else if (id < PR_WS0_END) { W = scale0; Wt = Ws0; K = 256;  N = T0_COLS; Npad = T0_PAD; scale = LOG2E; nx = 252;  rel = id - PR_WP1_END; }
  else                      { W = scale1; Wt = Ws1; K = 64;   N = T1_COLS; Npad = T1_PAD; scale = LOG2E; nx = 1260; rel = id - PR_WS0_END; }
  __shared__ float tile[32][33];
  const int n0 = (rel % nx) * 32, k0 = (rel / nx) * 32;
  const int tx = tid & 31, ty = tid >> 5;  // 32 x 8
  for (int i = 0; i < 32; i += 8) {
    int k = k0 + ty + i, n = n0 + tx;
    tile[ty + i][tx] = (n < N) ? W[(size_t)k * N + n] * scale : 0.f;
  }
  __syncthreads();
  // vectorized write: each thread emits 4 consecutive k as one 8 B store
  const int nloc = tid >> 3, kg = tid & 7;
  const int n = n0 + nloc;
  if (n < Npad) {
    union { unsigned short v[4]; uint2 u; } x;
#pragma unroll
    for (int j = 0; j < 4; j++) x.v[j] = f2bf(tile[kg * 4 + j][nloc]);
    *(uint2*)&Wt[(size_t)n * K + k0 + kg * 4] = x.u;
  }
}

// Shared 64-row x CI-cg x K=1024 MFMA K-loop. DOUBLE-BUFFERED: KC=128 in two
// 16 KB halves; chunk h+1's DMA is issued after the barrier so the next
// barrier's drain finds it landed.
template<int CI>
__device__ __forceinline__ void gemm64_kloop(
    unsigned short* A_lds,   // 2 x (64*128) ushorts = 32 KB
    const unsigned short* Arow,
    const unsigned short* const (&Bbase)[CI],
    floatx4 (&acc)[CI][4], int tid) {
  const int lane = tid & 63, w = tid >> 6;
  const int m = lane & 15, quad = lane >> 4, keym = m & 7;
  int goff[4];
#pragma unroll
  for (int it = 0; it < 4; it++) {
    int s = w * 256 + it * 64 + lane;
    int r = s >> 4, p = s & 15;
    int cq = p ^ (r & 7);
    goff[it] = r * CDIM + cq * 8;
  }
#pragma unroll
  for (int it = 0; it < 4; it++)
    stage16(Arow + goff[it], &A_lds[(w * 256 + it * 64) * 8], lane);
  for (int h = 0; h < 8; h++) {
    unsigned short* cur = A_lds + (h & 1) * (64 * 128);
    unsigned short* nxt = A_lds + ((h + 1) & 1) * (64 * 128);
    __syncthreads();
    if (h + 1 < 8) {
#pragma unroll
      for (int it = 0; it < 4; it++)
        stage16(Arow + goff[it] + (h + 1) * 128,
                &nxt[(w * 256 + it * 64) * 8], lane);
    }
    short8 b[CI][4];
#pragma unroll
    for (int ci = 0; ci < CI; ci++)
#pragma unroll
      for (int ks = 0; ks < 4; ks++)
        b[ci][ks] = *(const short8*)(Bbase[ci] + h * 128 + ks * 32);
    short8 areg[4][4];
#pragma unroll
    for (int t = 0; t < 4; t++)
#pragma unroll
      for (int ks = 0; ks < 4; ks++) {
        int ch = ((ks << 2) + quad) ^ keym;
        areg[t][ks] = *(const short8*)&cur[(t * 16 + m) * 128 + (ch << 3)];
      }
#pragma unroll
    for (int ci = 0; ci < CI; ci++)
#pragma unroll
      for (int ks = 0; ks < 4; ks++)
#pragma unroll
        for (int t = 0; t < 4; t++)
          acc[ci][t] = mfma16(areg[t][ks], b[ci][ks], acc[ci][t]);
  }
}

// Hidden projection: Hb[4096][320] = bf16(Lb @ Wp). CPS=1, grid (64,5).
__global__ __launch_bounds__(256) void gemm_hidden(
    const unsigned short* __restrict__ Lb,
    const unsigned short* __restrict__ Wp,
    unsigned short* __restrict__ Hb) {
  __shared__ unsigned short A_lds[64 * 256];  // 2 x 16 KB halves
  const int tid = threadIdx.x;
  const int row0 = blockIdx.x * 64;
  const int cg0 = blockIdx.y;
  const int lane = tid & 63, w = tid >> 6;
  const int m = lane & 15, quad = lane >> 4;
  const floatx4 zf = {0.f, 0.f, 0.f, 0.f};
  floatx4 acc[1][4];
#pragma unroll
  for (int t = 0; t < 4; t++) acc[0][t] = zf;
  const unsigned short* Bb[1] = {
      Wp + (size_t)(cg0 * 64 + w * 16 + m) * CDIM + quad * 8};
  gemm64_kloop<1>(A_lds, Lb + (size_t)row0 * CDIM, Bb, acc, tid);
  int n = cg0 * 64 + w * 16 + m;
  if (n < HB_STRIDE) {
#pragma unroll
    for (int t = 0; t < 4; t++)
#pragma unroll
      for (int r = 0; r < 4; r++)
        Hb[(size_t)(row0 + t * 16 + quad * 4 + r) * HB_STRIDE + n] =
            f2bf(acc[0][t][r]);
  }
}

// ---------------- mega kernel: root CE + tail1 + tail0 + picked ----------------
// LINEAR bid order (r14's prime-interleave raised FETCH 67->86 MB and
// regressed: it broke cross-chunk B locality in L2. Reverted.)
#define MG_ROOT 512           // 32 x-tiles (BM=128) x 16 cg-pairs
#define MG_T1   480           // 32 row-tiles (BM=128) x 15 y
#define MG_T0   2688          // 128 row-tiles x 21 y
#define MG_PICK 1024
#define MG_TOTAL (MG_ROOT + MG_T1 + MG_T0 + MG_PICK)

// Root CE, BM=128: halves the dominant B stream (1024 blocks x 256 KB Wh
// slice = 256 MB at BM=64 -> 128 MB at BM=128; mega is memory-stream-bound:
// r13 arithmetic 600 MB stream / ~6.5 TB/s ~= measured 99 us).
// 32 KB A-tile per chunk (128r x 128k), two 64-row halves reuse areg[4][4].
__device__ __forceinline__ void root_path(
    unsigned char* smem, int bx, int by,
    const unsigned short* __restrict__ Lb,
    const unsigned short* __restrict__ Wh, float* __restrict__ S) {
  unsigned short* A_lds = (unsigned short*)smem;  // 128*128 ushorts = 32 KB
  const int tid = threadIdx.x;
  const int row0 = bx * 128;
  const int cg0 = by * 2;
  const int lane = tid & 63, w = tid >> 6;
  const int m = lane & 15, quad = lane >> 4, keym = m & 7;
  const floatx4 zf = {0.f, 0.f, 0.f, 0.f};
  floatx4 acc[2][8];
#pragma unroll
  for (int ci = 0; ci < 2; ci++)
#pragma unroll
    for (int t = 0; t < 8; t++) acc[ci][t] = zf;
  const unsigned short* Bb[2] = {
      Wh + (size_t)((cg0 + 0) * 64 + w * 16 + m) * CDIM + quad * 8,
      Wh + (size_t)((cg0 + 1) * 64 + w * 16 + m) * CDIM + quad * 8};
  const unsigned short* Arow = Lb + (size_t)row0 * CDIM;
  // staging: slot s = w*512+it*64+lane -> row r=s>>4 (16 chunks/row),
  // phys p=s&15 stores logical cq = p^(r&7)
  int goff[8];
#pragma unroll
  for (int it = 0; it < 8; it++) {
    int s = w * 512 + it * 64 + lane;
    int r = s >> 4, p = s & 15;
    int cq = p ^ (r & 7);
    goff[it] = r * CDIM + cq * 8;
  }
  for (int h = 0; h < 8; h++) {
    // B prefetch: lands during the post-staging barrier's vmcnt drain
    short8 b[2][4];
#pragma unroll
    for (int ci = 0; ci < 2; ci++)
#pragma unroll
      for (int ks = 0; ks < 4; ks++)
        b[ci][ks] = *(const short8*)(Bb[ci] + h * 128 + ks * 32);
    __syncthreads();  // previous chunk's readers done
#pragma unroll
    for (int it = 0; it < 8; it++)
      stage16(Arow + goff[it] + h * 128, &A_lds[(w * 512 + it * 64) * 8], lane);
    __syncthreads();  // DMA drained
    short8 areg[4][4];
    // half 0: rows 0..63
#pragma unroll
    for (int t = 0; t < 4; t++)
#pragma unroll
      for (int ks = 0; ks < 4; ks++) {
        int ch = ((ks << 2) + quad) ^ keym;
        areg[t][ks] = *(const short8*)&A_lds[(t * 16 + m) * 128 + (ch << 3)];
      }
#pragma unroll
    for (int ci = 0; ci < 2; ci++)
#pragma unroll
      for (int ks = 0; ks < 4; ks++)
#pragma unroll
        for (int t = 0; t < 4; t++)
          acc[ci][t] = mfma16(areg[t][ks], b[ci][ks], acc[ci][t]);
    // half 1: rows 64..127
#pragma unroll
    for (int t = 0; t < 4; t++)
#pragma unroll
      for (int ks = 0; ks < 4; ks++) {
        int ch = ((ks << 2) + quad) ^ keym;
        areg[t][ks] = *(const short8*)&A_lds[(64 + t * 16 + m) * 128 + (ch << 3)];
      }
#pragma unroll
    for (int ci = 0; ci < 2; ci++)
#pragma unroll
      for (int ks = 0; ks < 4; ks++)
#pragma unroll
        for (int t = 0; t < 4; t++)
          acc[ci][4 + t] = mfma16(areg[t][ks], b[ci][ks], acc[ci][4 + t]);
  }
  // epilogue: reuse smem for 128 per-row sums
  __syncthreads();
  float* sums = (float*)smem;
  if (tid < 128) sums[tid] = 0.f;
  __syncthreads();
#pragma unroll
  for (int t = 0; t < 8; t++)
#pragma unroll
    for (int r = 0; r < 4; r++) {
      float e = __builtin_amdgcn_exp2f(acc[0][t][r]) +
                __builtin_amdgcn_exp2f(acc[1][t][r]);
      e += __shfl_xor(e, 1); e += __shfl_xor(e, 2);
      e += __shfl_xor(e, 4); e += __shfl_xor(e, 8);
      if (m == 0)
        atomicAdd(&sums[(t >> 2) * 64 + (t & 3) * 16 + quad * 4 + r], e);
    }
  __syncthreads();
  if (tid < 128) atomicAdd(&S[row0 + tid], sums[tid]);
}

// Tail CE path: A in regs, runtime cg loop, 2 cgs/iter through literally-
// indexed b0/b1 with 2-deep prefetch (r6/r9 register lessons).
template<int K, int TILES, int MODE>
__device__ __forceinline__ void tail_path(
    unsigned char* smem, int bx, int by,
    const unsigned short* __restrict__ Hb, int acol0,
    const unsigned short* __restrict__ Wt, int ncgpb,
    const int* __restrict__ idx, const int* __restrict__ cnt,
    float* __restrict__ S) {
  constexpr int BM = TILES * 16;
  constexpr int CpR = K / 8;
  constexpr int KS = K / 32;
  unsigned short* A_lds = (unsigned short*)smem;            // BM*K ushorts
  int* row_lds = (int*)(smem + (size_t)BM * K * 2);
  float* sum_lds = (float*)(smem + (size_t)BM * K * 2 + BM * 4);
  const int tid = threadIdx.x;
  const int count = cnt[MODE - 1];
  const int row0 = bx * BM;
  if (row0 >= count) return;
  if (tid < BM) {
    int r = row0 + tid;
    row_lds[tid] = (r < count) ? idx[r] : -1;
    sum_lds[tid] = 0.f;
  }
  __syncthreads();
#pragma unroll
  for (int i = 0; i < BM * CpR / 256; i++) {
    int c = tid + 256 * i;
    int rl = c / CpR, cq = c % CpR;
    int row = row_lds[rl];
    ushort8 v = {0, 0, 0, 0, 0, 0, 0, 0};
    if (row >= 0) v = *(const ushort8*)(Hb + (size_t)row * HB_STRIDE + acol0 + cq * 8);
    *(ushort8*)&A_lds[rl * K + ((cq ^ (rl & 7)) << 3)] = v;
  }
  __syncthreads();
  const int lane = tid & 63, w = tid >> 6;
  const int m = lane & 15, quad = lane >> 4, keym = m & 7;
  const floatx4 zf = {0.f, 0.f, 0.f, 0.f};
  short8 areg[TILES][KS];
#pragma unroll
  for (int t = 0; t < TILES; t++)
#pragma unroll
    for (int ks = 0; ks < KS; ks++) {
      int ch = ((ks << 2) + quad) ^ keym;
      areg[t][ks] = *(const short8*)&A_lds[(t * 16 + m) * K + (ch << 3)];
    }
  float runsum[TILES][4];
#pragma unroll
  for (int t = 0; t < TILES; t++)
#pragma unroll
    for (int r = 0; r < 4; r++) runsum[t][r] = 0.f;

  const int cg0 = by * ncgpb;
  const unsigned short* Bp = Wt + (size_t)(cg0 * 64 + w * 16 + m) * K + quad * 8;
  short8 b0[KS], b1[KS];
#pragma unroll
  for (int ks = 0; ks < KS; ks++) b0[ks] = *(const short8*)(Bp + ks * 32);
#pragma unroll
  for (int ks = 0; ks < KS; ks++)
    b1[ks] = *(const short8*)(Bp + (size_t)64 * K + ks * 32);

  for (int cc = 0; cc < ncgpb; cc += 2) {  // runtime loop, literal reg indices
    floatx4 acc[TILES];
#pragma unroll
    for (int t = 0; t < TILES; t++) acc[t] = zf;
#pragma unroll
    for (int ks = 0; ks < KS; ks++)
#pragma unroll
      for (int t = 0; t < TILES; t++) acc[t] = mfma16(areg[t][ks], b0[ks], acc[t]);
    if (cc + 2 < ncgpb) {
      const unsigned short* p = Bp + (size_t)(cc + 2) * 64 * K;
#pragma unroll
      for (int ks = 0; ks < KS; ks++) b0[ks] = *(const short8*)(p + ks * 32);
    }
#pragma unroll
    for (int t = 0; t < TILES; t++)
#pragma unroll
      for (int r = 0; r < 4; r++)
        runsum[t][r] += __builtin_amdgcn_exp2f(acc[t][r]);

#pragma unroll
    for (int t = 0; t < TILES; t++) acc[t] = zf;
#pragma unroll
    for (int ks = 0; ks < KS; ks++)
#pragma unroll
      for (int t = 0; t < TILES; t++) acc[t] = mfma16(areg[t][ks], b1[ks], acc[t]);
    if (cc + 3 < ncgpb) {
      const unsigned short* p = Bp + (size_t)(cc + 3) * 64 * K;
#pragma unroll
      for (int ks = 0; ks < KS; ks++) b1[ks] = *(const short8*)(p + ks * 32);
    }
#pragma unroll
    for (int t = 0; t < TILES; t++)
#pragma unroll
      for (int r = 0; r < 4; r++)
        runsum[t][r] += __builtin_amdgcn_exp2f(acc[t][r]);
  }

#pragma unroll
  for (int t = 0; t < TILES; t++)
#pragma unroll
    for (int r = 0; r < 4; r++) {
      float e = runsum[t][r];
      e += __shfl_xor(e, 1); e += __shfl_xor(e, 2);
      e += __shfl_xor(e, 4); e += __shfl_xor(e, 8);
      if (m == 0) atomicAdd(&sum_lds[t * 16 + quad * 4 + r], e);
    }
  __syncthreads();
  if (tid < BM) {
    int row = row_lds[tid];
    if (row >= 0) atomicAdd(&S[row], sum_lds[tid]);
  }
}

__device__ __forceinline__ void picked_path(
    int rel, const float* __restrict__ logits, const int* __restrict__ targets,
    const unsigned short* __restrict__ Wh,
    const unsigned short* __restrict__ Ws0,
    const unsigned short* __restrict__ Ws1,
    const unsigned short* __restrict__ Hb, float* __restrict__ P) {
  const int tid = threadIdx.x, lane = tid & 63;
  const int row = rel * 4 + (tid >> 6);
  const int t = targets[row];
  const int tr = (t >= T0_LO && t < T0_HI) ? T0_LO : ((t >= T1_LO) ? T0_LO + 1 : t);
  const float* a = logits + (size_t)row * CDIM + lane * 16;
  const unsigned short* wr = Wh + (size_t)tr * CDIM + lane * 16;
  float acc = 0.f;
#pragma unroll
  for (int q = 0; q < 2; q++) {
    ushort8 wv = *(const ushort8*)(wr + q * 8);
    float4 a0 = ((const float4*)a)[q * 2];
    float4 a1 = ((const float4*)a)[q * 2 + 1];
    acc += a0.x * bf2f(wv[0]) + a0.y * bf2f(wv[1]) + a0.z * bf2f(wv[2]) + a0.w * bf2f(wv[3]);
    acc += a1.x * bf2f(wv[4]) + a1.y * bf2f(wv[5]) + a1.z * bf2f(wv[6]) + a1.w * bf2f(wv[7]);
  }
#pragma unroll
  for (int off = 1; off < 64; off <<= 1) acc += __shfl_xor(acc, off);
  if (lane == 0) P[row] = acc * LN2;
  if (t >= T0_LO) {
    float acc2 = 0.f;
    if (t < T0_HI) {
      const unsigned short* h = Hb + (size_t)row * HB_STRIDE + lane * 4;
      const unsigned short* w2 = Ws0 + (size_t)(t - T0_LO) * 256 + lane * 4;
#pragma unroll
      for (int j = 0; j < 4; j++) acc2 += bf2f(h[j]) * bf2f(w2[j]);
    } else {
      acc2 = bf2f(Hb[(size_t)row * HB_STRIDE + 256 + lane]) *
             bf2f(Ws1[(size_t)(t - T1_LO) * 64 + lane]);
    }
#pragma unroll
    for (int off = 1; off < 64; off <<= 1) acc2 += __shfl_xor(acc2, off);
    if (lane == 0) P[(t < T0_HI ? NROWS : 2 * NROWS) + row] = acc2 * LN2;
  }
}

__global__ __launch_bounds__(256, 2) void mega_kernel(
    const unsigned short* __restrict__ Lb,
    const unsigned short* __restrict__ Wh,
    const unsigned short* __restrict__ Ws0,
    const unsigned short* __restrict__ Ws1,
    const unsigned short* __restrict__ Hb,
    const float* __restrict__ logits, const int* __restrict__ targets,
    const int* __restrict__ idx0, const int* __restrict__ idx1,
    const int* __restrict__ cnt, float* __restrict__ S, float* __restrict__ P) {
  __shared__ __align__(16) unsigned char smem[32768];
  int bid = blockIdx.x;
  if (bid < MG_ROOT) {  // BM=128: x = bid & 31, y = bid >> 5
    root_path(smem, bid & 31, bid >> 5, Lb, Wh, S);
    return;
  }
  bid -= MG_ROOT;
  if (bid < MG_T1) {  // BM=128: x = bid & 31 (row-tile fastest -> B L2-hot)
    tail_path<64, 8, 2>(smem, bid & 31, bid >> 5, Hb, 256, Ws1, 42, idx1, cnt,
                        S + 2 * NROWS);
    return;
  }
  bid -= MG_T1;
  if (bid < MG_T0) {
    tail_path<256, 2, 1>(smem, bid & 127, bid >> 7, Hb, 0, Ws0, 6, idx0, cnt,
                         S + NROWS);
    return;
  }
  bid -= MG_T0;
  picked_path(bid, logits, targets, Wh, Ws0, Ws1, Hb, P);
}

__global__ void loss_kernel(const int* __restrict__ targets,
                            const float* __restrict__ S,   // [3][NROWS]
                            const float* __restrict__ P,   // [3][NROWS]
                            float* __restrict__ out) {
  const int tid = threadIdx.x;
  float sr = 0.f, s0 = 0.f, s1 = 0.f, c0 = 0.f, c1 = 0.f;
  for (int n = tid; n < NROWS; n += 256) {
    int t = targets[n];
    sr += logf(S[n] - 46.f) - P[n];  // 46 root pad cols -> exp2(0)=1 each
    if (t >= T0_LO && t < T0_HI) { s0 += logf(S[NROWS + n] - 64.f) - P[NROWS + n]; c0 += 1.f; }
    else if (t >= T1_LO)         { s1 += logf(S[2 * NROWS + n] - 63.f) - P[2 * NROWS + n]; c1 += 1.f; }
  }
  for (int off = 32; off > 0; off >>= 1) {
    sr += __shfl_down(sr, off);
    s0 += __shfl_down(s0, off);
    s1 += __shfl_down(s1, off);
    c0 += __shfl_down(c0, off);
    c1 += __shfl_down(c1, off);
  }
  __shared__ float red[4][5];
  int wv = tid >> 6;
  if ((tid & 63) == 0) { red[wv][0] = sr; red[wv][1] = s0; red[wv][2] = s1; red[wv][3] = c0; red[wv][4] = c1; }
  __syncthreads();
  if (tid == 0) {
    sr = red[0][0] + red[1][0] + red[2][0] + red[3][0];
    s0 = red[0][1] + red[1][1] + red[2][1] + red[3][1];
    s1 = red[0][2] + red[1][2] + red[2][2] + red[3][2];
    c0 = red[0][3] + red[1][3] + red[2][3] + red[3][3];
    c1 = red[0][4] + red[1][4] + red[2][4] + red[3][4];
    float root_loss = sr / (float)NROWS;
    float l0 = s0 / fmaxf(c0, 1.f);
    float l1 = s1 / fmaxf(c1, 1.f);
    out[0] = (root_loss + l0 + l1) / 3.f;
  }
}

extern "C" void kernel_launch(void* const* d_in, const int* in_sizes, int n_in,
                              void* d_out, int out_size, void* d_ws, size_t ws_size,
                              hipStream_t stream) {
  const float* logits  = (const float*)d_in[0];
  const int*   targets = (const int*)d_in[1];
  const float* head    = (const float*)d_in[2];
  const float* proj0   = (const float*)d_in[3];
  const float* scale0  = (const float*)d_in[4];
  const float* proj1   = (const float*)d_in[5];
  const float* scale1  = (const float*)d_in[6];
  float* out = (float*)d_out;
  char* ws = (char*)d_ws;

  unsigned short* Hb  = (unsigned short*)(ws + B_HB);
  unsigned short* Lb  = (unsigned short*)(ws + B_LB);
  unsigned short* Wp  = (unsigned short*)(ws + B_WP);
  unsigned short* Wh  = (unsigned short*)(ws + B_WH);
  unsigned short* Ws0 = (unsigned short*)(ws + B_WS0);
  unsigned short* Ws1 = (unsigned short*)(ws + B_WS1);
  float* S = (float*)(ws + B_S);
  float* P = (float*)(ws + B_P);
  int* idx0 = (int*)(ws + B_I0);
  int* idx1 = (int*)(ws + B_I1);
  int* cnt  = (int*)(ws + B_CNT);

  prep_kernel<<<PR_TOTAL, 256, 0, stream>>>(head, proj0, proj1, scale0, scale1,
                                            logits, targets, Wh, Wp, Ws0, Ws1,
                                            Lb, S, idx0, idx1, cnt);
  gemm_hidden<<<dim3(64, 5), 256, 0, stream>>>(Lb, Wp, Hb);
  mega_kernel<<<MG_TOTAL, 256, 0, stream>>>(Lb, Wh, Ws0, Ws1, Hb, logits,
                                            targets, idx0, idx1, cnt, S, P);
  loss_kernel<<<1, 256, 0, stream>>>(targets, S, P, out);
}